// Round 1
// baseline (162.627 us; speedup 1.0000x reference)
//
#include <hip/hip_runtime.h>
#include <hip/hip_bf16.h>
#include <cstdint>

#define IN_F 256
#define OUT_F 64
#define NB 4
#define NN 4096
#define ALPHA 0.2f
#define MASK_VAL -9e15f

typedef __attribute__((ext_vector_type(4))) float f32x4;
typedef __attribute__((ext_vector_type(4))) int i32x4;
typedef __attribute__((ext_vector_type(8))) short bf16x8;

static __device__ __forceinline__ ushort f2bf(float x) {
  uint32_t u = __float_as_uint(x);
  uint32_t r = (u + 0x7fffu + ((u >> 16) & 1u)) >> 16;
  return (ushort)r;
}

// ---------------- Kernel 1: Wh = h@W + bias; Wh1/Wh2 = Wh.a1/a2; WhT (bf16, [B][64][N])
#define K1_ROWS 64
__global__ __launch_bounds__(256) void k1_gemm(
    const float* __restrict__ h, const float* __restrict__ W,
    const float* __restrict__ a, const float* __restrict__ bias,
    ushort* __restrict__ WhT, float* __restrict__ Wh1, float* __restrict__ Wh2)
{
  __shared__ float hs[K1_ROWS][33];
  __shared__ float Ws[32][64];
  const int t  = threadIdx.x;
  const int tx = t & 15;        // col group: cols tx*4..tx*4+3
  const int ty = t >> 4;        // row group: rows ty*4..ty*4+3
  const int row0 = blockIdx.x * K1_ROWS;

  float acc[4][4] = {};

  for (int k0 = 0; k0 < IN_F; k0 += 32) {
    #pragma unroll
    for (int s = 0; s < 2; ++s) {                 // h tile: 64x32
      int f4 = t + 256 * s;
      int r = f4 >> 3, c4 = f4 & 7;
      f32x4 v = *(const f32x4*)(h + (size_t)(row0 + r) * IN_F + k0 + c4 * 4);
      *(f32x4*)&hs[r][c4 * 4] = v;
    }
    #pragma unroll
    for (int s = 0; s < 2; ++s) {                 // W tile: 32x64
      int f4 = t + 256 * s;
      int kk = f4 >> 4, c4 = f4 & 15;
      *(f32x4*)&Ws[kk][c4 * 4] = *(const f32x4*)(W + (size_t)(k0 + kk) * OUT_F + c4 * 4);
    }
    __syncthreads();
    #pragma unroll 8
    for (int kk = 0; kk < 32; ++kk) {
      f32x4 bv = *(const f32x4*)&Ws[kk][tx * 4];
      #pragma unroll
      for (int i = 0; i < 4; ++i) {
        float av = hs[ty * 4 + i][kk];
        acc[i][0] += av * bv[0];
        acc[i][1] += av * bv[1];
        acc[i][2] += av * bv[2];
        acc[i][3] += av * bv[3];
      }
    }
    __syncthreads();
  }

  // epilogue: bias, Wh1/Wh2 row dots, WhT bf16 writes
  #pragma unroll
  for (int i = 0; i < 4; ++i) {
    int row = row0 + ty * 4 + i;
    float s1 = 0.f, s2 = 0.f;
    #pragma unroll
    for (int j = 0; j < 4; ++j) {
      float v = acc[i][j] + bias[tx * 4 + j];
      acc[i][j] = v;
      s1 += v * a[tx * 4 + j];
      s2 += v * a[64 + tx * 4 + j];
    }
    #pragma unroll
    for (int off = 1; off < 16; off <<= 1) {
      s1 += __shfl_xor(s1, off);
      s2 += __shfl_xor(s2, off);
    }
    if (tx == 0) { Wh1[row] = s1; Wh2[row] = s2; }
    int bb = row >> 12;
    int n  = row & 4095;
    #pragma unroll
    for (int j = 0; j < 4; ++j) {
      WhT[(((size_t)(bb * OUT_F + tx * 4 + j)) << 12) + n] = f2bf(acc[i][j]);
    }
  }
}

// ---------------- Kernel 1b: M2[b] = max_j Wh2[b,j]
__global__ __launch_bounds__(256) void k1b_max(const float* __restrict__ Wh2,
                                               float* __restrict__ M2)
{
  const int b = blockIdx.x;
  float m = -3.0e38f;
  for (int i = threadIdx.x; i < NN; i += 256) m = fmaxf(m, Wh2[(b << 12) + i]);
  #pragma unroll
  for (int off = 1; off < 64; off <<= 1) m = fmaxf(m, __shfl_xor(m, off));
  __shared__ float sm[4];
  if ((threadIdx.x & 63) == 0) sm[threadIdx.x >> 6] = m;
  __syncthreads();
  if (threadIdx.x == 0) M2[b] = fmaxf(fmaxf(sm[0], sm[1]), fmaxf(sm[2], sm[3]));
}

// ---------------- Kernel 2: fused masked softmax + PV (flash-style, no LDS, no barriers)
// grid (NN/32, NB), 256 threads (4 waves). Block: 32 rows x 64 cols output.
__global__ __launch_bounds__(256) void k2_attn(
    const int* __restrict__ adj, const ushort* __restrict__ WhT,
    const float* __restrict__ Wh1, const float* __restrict__ Wh2,
    const float* __restrict__ M2, float* __restrict__ out)
{
  const int l  = threadIdx.x & 63;
  const int w  = threadIdx.x >> 6;
  const int wm = w >> 1;              // row half (0/1)
  const int wn = w & 1;               // col half (0/1)
  const int b  = blockIdx.y;
  const int r0 = blockIdx.x * 32;
  const int g  = l >> 4;              // k-group 0..3
  const int lr = l & 15;
  const int arow = r0 + wm * 16 + lr; // A-fragment row for this lane

  const float wh1 = Wh1[(b << 12) + arow];
  float mrow = wh1 + M2[b];
  mrow = mrow > 0.f ? mrow : ALPHA * mrow;   // = unmasked row max (valid softmax shift)

  const int*    adjp = adj  + ((size_t)b << 24) + ((size_t)arow << 12) + g * 8;
  const float*  wh2p = Wh2  + (b << 12) + g * 8;
  const ushort* btp0 = WhT  + (((size_t)(b * OUT_F + wn * 32 + lr)) << 12) + g * 8;
  const ushort* btp1 = btp0 + ((size_t)16 << 12);

  f32x4 acc0 = {0.f, 0.f, 0.f, 0.f};
  f32x4 acc1 = {0.f, 0.f, 0.f, 0.f};
  float psum = 0.f;

  #pragma unroll 4
  for (int j0 = 0; j0 < NN; j0 += 32) {
    i32x4 ad0 = *(const i32x4*)(adjp);
    i32x4 ad1 = *(const i32x4*)(adjp + 4);
    f32x4 w20 = *(const f32x4*)(wh2p);
    f32x4 w21 = *(const f32x4*)(wh2p + 4);
    bf16x8 bf0 = *(const bf16x8*)(btp0);
    bf16x8 bf1 = *(const bf16x8*)(btp1);

    float p[8];
    #pragma unroll
    for (int i = 0; i < 8; ++i) {
      float w2 = (i < 4) ? w20[i] : w21[i - 4];
      int   am = (i < 4) ? ad0[i] : ad1[i - 4];
      float s = wh1 + w2;
      float e = s > 0.f ? s : ALPHA * s;
      e = (am > 0) ? e : MASK_VAL;
      float pv = __expf(e - mrow);   // masked -> exp(-huge) = 0
      psum += pv;
      p[i] = pv;
    }
    bf16x8 af;
    #pragma unroll
    for (int i = 0; i < 8; ++i) af[i] = (short)f2bf(p[i]);

    acc0 = __builtin_amdgcn_mfma_f32_16x16x32_bf16(af, bf0, acc0, 0, 0, 0);
    acc1 = __builtin_amdgcn_mfma_f32_16x16x32_bf16(af, bf1, acc1, 0, 0, 0);

    adjp += 32; wh2p += 32; btp0 += 32; btp1 += 32;
  }

  // row sums: lanes lr, lr+16, lr+32, lr+48 hold k-quarters of row (r0+wm*16+lr)
  psum += __shfl_xor(psum, 16);
  psum += __shfl_xor(psum, 32);

  // C/D layout: col = lane&15, row = 4*(lane>>4)+r  (m89-verified)
  #pragma unroll
  for (int r = 0; r < 4; ++r) {
    int orow = r0 + wm * 16 + g * 4 + r;
    float rs = __shfl(psum, g * 4 + r, 64);
    float inv = 1.0f / rs;
    float x0 = acc0[r] * inv;
    float x1 = acc1[r] * inv;
    float o0 = x0 > 0.f ? x0 : expm1f(x0);
    float o1 = x1 > 0.f ? x1 : expm1f(x1);
    size_t base = (((size_t)(b << 12) + orow) << 6);
    out[base + wn * 32 + lr]      = o0;
    out[base + wn * 32 + 16 + lr] = o1;
  }
}

extern "C" void kernel_launch(void* const* d_in, const int* in_sizes, int n_in,
                              void* d_out, int out_size, void* d_ws, size_t ws_size,
                              hipStream_t stream) {
  const float* h    = (const float*)d_in[0];
  const int*   adj  = (const int*)d_in[1];
  const float* W    = (const float*)d_in[2];
  const float* a    = (const float*)d_in[3];
  const float* bias = (const float*)d_in[4];
  float* out = (float*)d_out;

  char* ws = (char*)d_ws;
  ushort* WhT = (ushort*)ws;                                   // 4*64*4096*2 = 2 MB
  float*  Wh1 = (float*)(ws + (size_t)NB * OUT_F * NN * 2);    // 64 KB
  float*  Wh2 = Wh1 + NB * NN;                                 // 64 KB
  float*  M2  = Wh2 + NB * NN;                                 // 16 B

  k1_gemm<<<dim3(NB * NN / K1_ROWS), 256, 0, stream>>>(h, W, a, bias, WhT, Wh1, Wh2);
  k1b_max<<<dim3(NB), 256, 0, stream>>>(Wh2, M2);
  k2_attn<<<dim3(NN / 32, NB), 256, 0, stream>>>(adj, WhT, Wh1, Wh2, M2, out);
}

// Round 2
// 134.249 us; speedup vs baseline: 1.2114x; 1.2114x over previous
//
#include <hip/hip_runtime.h>
#include <hip/hip_bf16.h>
#include <cstdint>

#define IN_F 256
#define OUT_F 64
#define NB 4
#define NN 4096
#define ALPHA 0.2f

typedef __attribute__((ext_vector_type(4))) float f32x4;
typedef __attribute__((ext_vector_type(4))) int i32x4;
typedef __attribute__((ext_vector_type(8))) short bf16x8;

#if __has_builtin(__builtin_amdgcn_exp2f)
#define EXP2(x) __builtin_amdgcn_exp2f(x)
#else
#define EXP2(x) exp2f(x)
#endif

static __device__ __forceinline__ ushort f2bf(float x) {
  uint32_t u = __float_as_uint(x);
  uint32_t r = (u + 0x7fffu + ((u >> 16) & 1u)) >> 16;
  return (ushort)r;
}

// ---------------- Kernel 1: Wh = h@W + bias; Wh1/Wh2 = Wh.a1/a2; WhT (bf16, [B][64][N])
#define K1_ROWS 64
__global__ __launch_bounds__(256) void k1_gemm(
    const float* __restrict__ h, const float* __restrict__ W,
    const float* __restrict__ a, const float* __restrict__ bias,
    ushort* __restrict__ WhT, float* __restrict__ Wh1, float* __restrict__ Wh2)
{
  __shared__ float hs[K1_ROWS][33];
  __shared__ float Ws[32][64];
  const int t  = threadIdx.x;
  const int tx = t & 15;        // col group: cols tx*4..tx*4+3
  const int ty = t >> 4;        // row group: rows ty*4..ty*4+3
  const int row0 = blockIdx.x * K1_ROWS;

  float acc[4][4] = {};

  for (int k0 = 0; k0 < IN_F; k0 += 32) {
    #pragma unroll
    for (int s = 0; s < 2; ++s) {                 // h tile: 64x32
      int f4 = t + 256 * s;
      int r = f4 >> 3, c4 = f4 & 7;
      f32x4 v = *(const f32x4*)(h + (size_t)(row0 + r) * IN_F + k0 + c4 * 4);
      *(f32x4*)&hs[r][c4 * 4] = v;
    }
    #pragma unroll
    for (int s = 0; s < 2; ++s) {                 // W tile: 32x64
      int f4 = t + 256 * s;
      int kk = f4 >> 4, c4 = f4 & 15;
      *(f32x4*)&Ws[kk][c4 * 4] = *(const f32x4*)(W + (size_t)(k0 + kk) * OUT_F + c4 * 4);
    }
    __syncthreads();
    #pragma unroll 8
    for (int kk = 0; kk < 32; ++kk) {
      f32x4 bv = *(const f32x4*)&Ws[kk][tx * 4];
      #pragma unroll
      for (int i = 0; i < 4; ++i) {
        float av = hs[ty * 4 + i][kk];
        acc[i][0] += av * bv[0];
        acc[i][1] += av * bv[1];
        acc[i][2] += av * bv[2];
        acc[i][3] += av * bv[3];
      }
    }
    __syncthreads();
  }

  // epilogue: bias, Wh1/Wh2 row dots, WhT bf16 writes
  #pragma unroll
  for (int i = 0; i < 4; ++i) {
    int row = row0 + ty * 4 + i;
    float s1 = 0.f, s2 = 0.f;
    #pragma unroll
    for (int j = 0; j < 4; ++j) {
      float v = acc[i][j] + bias[tx * 4 + j];
      acc[i][j] = v;
      s1 += v * a[tx * 4 + j];
      s2 += v * a[64 + tx * 4 + j];
    }
    #pragma unroll
    for (int off = 1; off < 16; off <<= 1) {
      s1 += __shfl_xor(s1, off);
      s2 += __shfl_xor(s2, off);
    }
    if (tx == 0) { Wh1[row] = s1; Wh2[row] = s2; }
    int bb = row >> 12;
    int n  = row & 4095;
    #pragma unroll
    for (int j = 0; j < 4; ++j) {
      WhT[(((size_t)(bb * OUT_F + tx * 4 + j)) << 12) + n] = f2bf(acc[i][j]);
    }
  }
}

// ---------------- Kernel 1b: M2[b] = max_j Wh2[b,j]
__global__ __launch_bounds__(256) void k1b_max(const float* __restrict__ Wh2,
                                               float* __restrict__ M2)
{
  const int b = blockIdx.x;
  float m = -3.0e38f;
  for (int i = threadIdx.x; i < NN; i += 256) m = fmaxf(m, Wh2[(b << 12) + i]);
  #pragma unroll
  for (int off = 1; off < 64; off <<= 1) m = fmaxf(m, __shfl_xor(m, off));
  __shared__ float sm[4];
  if ((threadIdx.x & 63) == 0) sm[threadIdx.x >> 6] = m;
  __syncthreads();
  if (threadIdx.x == 0) M2[b] = fmaxf(fmaxf(sm[0], sm[1]), fmaxf(sm[2], sm[3]));
}

// ---------------- Kernel 2: fused masked softmax + PV
// grid (NN/16, NB), 256 threads = 4 waves. Block: 16 rows x 64 cols.
// Waves split K: wave w owns columns [w*1024, (w+1)*1024). Row sums via a
// 5th MFMA with B = ones (denominator shares bf16 rounding with numerator).
// Cross-wave combine in LDS epilogue.
__global__ __launch_bounds__(256, 4) void k2_attn(
    const int* __restrict__ adj, const ushort* __restrict__ WhT,
    const float* __restrict__ Wh1, const float* __restrict__ Wh2,
    const float* __restrict__ M2, float* __restrict__ out)
{
  const int t  = threadIdx.x;
  const int l  = t & 63;
  const int w  = t >> 6;              // K-chunk index 0..3
  const int b  = blockIdx.y;
  const int r0 = blockIdx.x << 4;
  const int g  = l >> 4;              // k-subgroup 0..3
  const int lr = l & 15;
  const int arow = r0 + lr;           // A row (= C col) for this lane

  const float LOG2E = 1.4426950408889634f;
  const float wh1 = Wh1[(b << 12) + arow];
  float mr = wh1 + M2[b];
  mr = mr > 0.f ? mr : ALPHA * mr;    // unmasked row max (valid softmax shift, exp<=1)
  const float nm2 = -mr * LOG2E;

  const int*    adjp = adj + ((size_t)b << 24) + ((size_t)arow << 12) + (w << 10) + (g << 3);
  const float*  wh2p = Wh2 + (b << 12) + (w << 10) + (g << 3);
  const ushort* btp  = WhT + (((size_t)(b * OUT_F + lr)) << 12) + (w << 10) + (g << 3);

  f32x4 acc0 = {0.f,0.f,0.f,0.f}, acc1 = {0.f,0.f,0.f,0.f};
  f32x4 acc2 = {0.f,0.f,0.f,0.f}, acc3 = {0.f,0.f,0.f,0.f};
  f32x4 accs = {0.f,0.f,0.f,0.f};
  bf16x8 ones;
  #pragma unroll
  for (int i = 0; i < 8; ++i) ones[i] = (short)0x3F80;   // bf16 1.0

  for (int it = 0; it < 32; ++it) {
    i32x4 ad0 = *(const i32x4*)(adjp);
    i32x4 ad1 = *(const i32x4*)(adjp + 4);
    f32x4 w20 = *(const f32x4*)(wh2p);
    f32x4 w21 = *(const f32x4*)(wh2p + 4);
    bf16x8 bfr0 = *(const bf16x8*)(btp);
    bf16x8 bfr1 = *(const bf16x8*)(btp + (16 << 12));
    bf16x8 bfr2 = *(const bf16x8*)(btp + (32 << 12));
    bf16x8 bfr3 = *(const bf16x8*)(btp + (48 << 12));

    float p[8];
    #pragma unroll
    for (int i = 0; i < 8; ++i) {
      float w2 = (i < 4) ? w20[i] : w21[i - 4];
      int   am = (i < 4) ? ad0[i] : ad1[i - 4];
      float s  = wh1 + w2;
      float lk = fmaf(ALPHA, fminf(s, 0.f), fmaxf(s, 0.f));  // LeakyReLU
      float pe = EXP2(fmaf(lk, LOG2E, nm2));
      p[i] = pe * (float)am;            // adj in {0,1}: mask by multiply
    }
    union { bf16x8 v; uint32_t u[4]; } af;
    #pragma unroll
    for (int i = 0; i < 4; ++i)
      asm("v_cvt_pk_bf16_f32 %0, %1, %2" : "=v"(af.u[i]) : "v"(p[2*i]), "v"(p[2*i+1]));

    accs = __builtin_amdgcn_mfma_f32_16x16x32_bf16(af.v, ones, accs, 0, 0, 0);
    acc0 = __builtin_amdgcn_mfma_f32_16x16x32_bf16(af.v, bfr0, acc0, 0, 0, 0);
    acc1 = __builtin_amdgcn_mfma_f32_16x16x32_bf16(af.v, bfr1, acc1, 0, 0, 0);
    acc2 = __builtin_amdgcn_mfma_f32_16x16x32_bf16(af.v, bfr2, acc2, 0, 0, 0);
    acc3 = __builtin_amdgcn_mfma_f32_16x16x32_bf16(af.v, bfr3, acc3, 0, 0, 0);

    adjp += 32; wh2p += 32; btp += 32;
  }

  // epilogue: cross-wave (K-chunk) reduction in LDS
  __shared__ float sacc[4][16][65];    // [wave][row][col], padded: conflict-free
  __shared__ float ssum[4][16];
  // C/D layout: col = lane&15 (= A row), row = 4*(lane>>4)+r
  #pragma unroll
  for (int r = 0; r < 4; ++r) {
    sacc[w][g * 4 + r][ 0 + lr] = acc0[r];
    sacc[w][g * 4 + r][16 + lr] = acc1[r];
    sacc[w][g * 4 + r][32 + lr] = acc2[r];
    sacc[w][g * 4 + r][48 + lr] = acc3[r];
  }
  if (lr == 0) {
    #pragma unroll
    for (int r = 0; r < 4; ++r) ssum[w][g * 4 + r] = accs[r];
  }
  __syncthreads();

  #pragma unroll
  for (int i = 0; i < 4; ++i) {
    int e   = t + (i << 8);
    int row = e >> 6, col = e & 63;
    float s = sacc[0][row][col] + sacc[1][row][col] + sacc[2][row][col] + sacc[3][row][col];
    float d = ssum[0][row] + ssum[1][row] + ssum[2][row] + ssum[3][row];
    float x = s / d;
    float o = x > 0.f ? x : expm1f(x);   // ELU
    out[(((size_t)(b << 12) + r0 + row) << 6) + col] = o;
  }
}

extern "C" void kernel_launch(void* const* d_in, const int* in_sizes, int n_in,
                              void* d_out, int out_size, void* d_ws, size_t ws_size,
                              hipStream_t stream) {
  const float* h    = (const float*)d_in[0];
  const int*   adj  = (const int*)d_in[1];
  const float* W    = (const float*)d_in[2];
  const float* a    = (const float*)d_in[3];
  const float* bias = (const float*)d_in[4];
  float* out = (float*)d_out;

  char* ws = (char*)d_ws;
  ushort* WhT = (ushort*)ws;                                   // 4*64*4096*2 = 2 MB
  float*  Wh1 = (float*)(ws + (size_t)NB * OUT_F * NN * 2);    // 64 KB
  float*  Wh2 = Wh1 + NB * NN;                                 // 64 KB
  float*  M2  = Wh2 + NB * NN;                                 // 16 B

  k1_gemm<<<dim3(NB * NN / K1_ROWS), 256, 0, stream>>>(h, W, a, bias, WhT, Wh1, Wh2);
  k1b_max<<<dim3(NB), 256, 0, stream>>>(Wh2, M2);
  k2_attn<<<dim3(NN / 16, NB), 256, 0, stream>>>(adj, WhT, Wh1, Wh2, M2, out);
}